// Round 6
// baseline (22014.403 us; speedup 1.0000x reference)
//
#include <hip/hip_runtime.h>

constexpr int F_ = 36;
constexpr int H_ = 512;
constexpr int B_ = 64;
constexpr int T_ = 1500;
constexpr int C_ = 64;
constexpr int NWG = 128;          // 4 hidden units per layer per WG
constexpr int BLK = 512;
constexpr int NW = 8;

constexpr int RING_U32 = H_ * B_;     // 32768 u32 per ring
constexpr size_t BAR_U32 = 128;       // done[128] epoch flags

#define SCOPE_AGENT __HIP_MEMORY_SCOPE_AGENT

typedef __attribute__((ext_vector_type(8))) short bf16x8;
typedef __attribute__((ext_vector_type(4))) float f32x4;

// ---- cross-XCD primitives (LLC coherence point, R5-proven protocol) ----
__device__ __forceinline__ void astore_u32(unsigned* p, unsigned v) {
    __hip_atomic_store(p, v, __ATOMIC_RELAXED, SCOPE_AGENT);
}
__device__ __forceinline__ uint4 llc_load4(const unsigned* p) {
    uint4 r;
    asm volatile("global_load_dwordx4 %0, %1, off sc0 sc1" : "=v"(r) : "v"(p));
    return r;
}
__device__ __forceinline__ uint2 llc_load2(const unsigned* p) {
    uint2 r;
    asm volatile("global_load_dwordx2 %0, %1, off sc0 sc1" : "=v"(r) : "v"(p));
    return r;
}
__device__ __forceinline__ void vm_wait0() {
    asm volatile("s_waitcnt vmcnt(0)" ::: "memory");
    __builtin_amdgcn_sched_barrier(0);
}
__device__ __forceinline__ void vm_wait8() {
    asm volatile("s_waitcnt vmcnt(8)" ::: "memory");
    __builtin_amdgcn_sched_barrier(0);
}

__device__ __forceinline__ float sigm(float x) { return 1.0f / (1.0f + __expf(-x)); }
__device__ __forceinline__ float tanhf_(float x) { return 1.0f - 2.0f / (__expf(2.0f * x) + 1.0f); }

// ---- bf16 hi/lo split machinery ----
__device__ __forceinline__ unsigned bf16rne(float f) {        // RNE bf16 (finite inputs)
    unsigned u = __float_as_uint(f);
    return (u + 0x7FFFu + ((u >> 16) & 1u)) >> 16;
}
// h -> u32: low16 = bf16(h), high16 = bf16(h - f32(hi))
__device__ __forceinline__ unsigned packhl(float h) {
    unsigned hi = bf16rne(h);
    float lo = h - __uint_as_float(hi << 16);
    return hi | (bf16rne(lo) << 16);
}

struct Frag2 { bf16x8 hi, lo; };

__device__ __forceinline__ Frag2 split8(const float v[8]) {
    union { unsigned u[4]; bf16x8 x; } hi, lo;
    #pragma unroll
    for (int j = 0; j < 4; ++j) {
        unsigned a = bf16rne(v[2*j]), b = bf16rne(v[2*j+1]);
        float ra = v[2*j]   - __uint_as_float(a << 16);
        float rb = v[2*j+1] - __uint_as_float(b << 16);
        hi.u[j] = a | (b << 16);
        lo.u[j] = bf16rne(ra) | (bf16rne(rb) << 16);
    }
    return { hi.x, lo.x };
}
// 8 packed u32 (k ascending) -> hi/lo bf16x8 frags (element 2j in low half of word j)
__device__ __forceinline__ Frag2 fromPacked(const uint4& q0, const uint4& q1) {
    unsigned p[8] = { q0.x, q0.y, q0.z, q0.w, q1.x, q1.y, q1.z, q1.w };
    union { unsigned u[4]; bf16x8 x; } hi, lo;
    #pragma unroll
    for (int j = 0; j < 4; ++j) {
        hi.u[j] = (p[2*j] & 0xFFFFu) | (p[2*j+1] << 16);
        lo.u[j] = (p[2*j] >> 16) | (p[2*j+1] & 0xFFFF0000u);
    }
    return { hi.x, lo.x };
}
// (Ahi+Alo)·(Bhi+Blo) dropping lo·lo (~2^-18 rel): 3 MFMAs
__device__ __forceinline__ f32x4 mfma3(const Frag2& a, const Frag2& b, f32x4 c) {
    c = __builtin_amdgcn_mfma_f32_16x16x32_bf16(a.hi, b.hi, c, 0, 0, 0);
    c = __builtin_amdgcn_mfma_f32_16x16x32_bf16(a.hi, b.lo, c, 0, 0, 0);
    c = __builtin_amdgcn_mfma_f32_16x16x32_bf16(a.lo, b.hi, c, 0, 0, 0);
    return c;
}
// A-frag gather: lane row = l&15, k = colbase + (l>>4)*8 + e  (cols >= ncols -> 0)
__device__ Frag2 gatherA(const float* W, int rstride, int grow, int colbase, int ncols, int kq) {
    float v[8];
    #pragma unroll
    for (int e = 0; e < 8; ++e) {
        int col = colbase + kq * 8 + e;
        v[e] = (col < ncols) ? W[(size_t)grow * rstride + col] : 0.0f;
    }
    return split8(v);
}

__global__ void __launch_bounds__(BLK, 1) lstm_all(
    const float* __restrict__ x,
    const float* __restrict__ Wih0, const float* __restrict__ Whh0,
    const float* __restrict__ bih0, const float* __restrict__ bhh0,
    const float* __restrict__ Wih1, const float* __restrict__ Whh1,
    const float* __restrict__ bih1, const float* __restrict__ bhh1,
    const float* __restrict__ Wout, const float* __restrict__ bout,
    float* __restrict__ out, unsigned* __restrict__ wsu)
{
    const int w = blockIdx.x;
    const int tid = threadIdx.x;
    const int v = tid >> 6;          // wave 0..7
    const int lane = tid & 63;
    const int bl = lane & 15;        // batch-local (B frag col / also A row idx)
    const int kq = lane >> 4;        // k-quarter within frag

    __shared__ float parts[NW][2][4][4][65];   // [wave][layer][bt][reg][lane(+pad)]
    __shared__ float cs[2][4][64];             // cell state  [layer][unit][b]
    __shared__ float bias[2][4][4];            // [layer][gate][unit]

    unsigned* done = wsu;
    unsigned* h1r[2] = { wsu + BAR_U32, wsu + BAR_U32 + RING_U32 };
    unsigned* h2r[2] = { wsu + BAR_U32 + 2 * RING_U32, wsu + BAR_U32 + 3 * RING_U32 };

    // ---- init: zero rings (packed bf16 zeros), cell state, bias ----
    {
        const int gstride = NWG * BLK;
        for (int i = w * BLK + tid; i < 4 * RING_U32; i += gstride)
            astore_u32(wsu + BAR_U32 + i, 0u);
    }
    ((float*)cs)[tid < 512 ? tid : 0] = 0.0f;   // 2*4*64 == 512 == BLK
    if (tid < 32) {
        int layer = tid >> 4, g = (tid >> 2) & 3, u = tid & 3;
        int grow = g * H_ + w * 4 + u;
        bias[layer][g][u] = layer ? (bih1[grow] + bhh1[grow]) : (bih0[grow] + bhh0[grow]);
    }

    // ---- one-time A-fragment setup (weights stay in VGPRs forever) ----
    // A row r = l&15 encodes (gate g = r>>2, unit u = r&3); grow = g*H + 4w + u
    const int rA = bl;
    const int grow = (rA >> 2) * H_ + w * 4 + (rA & 3);
    Frag2 A10[2], A11[2], A21[2], Ax;
    #pragma unroll
    for (int i = 0; i < 2; ++i) {
        int cb = (2 * v + i) * 32;                       // wave v owns k-tiles 2v, 2v+1
        A10[i] = gatherA(Whh0, H_, grow, cb, H_, kq);    // layer0 recurrence
        A11[i] = gatherA(Wih1, H_, grow, cb, H_, kq);    // layer1 input (same h1 B-frags!)
        A21[i] = gatherA(Whh1, H_, grow, cb, H_, kq);    // layer1 recurrence
    }
    Ax = (v < 2) ? gatherA(Wih0, F_, grow, v * 32, F_, kq)
                 : gatherA(Wih0, F_, 0, 0, 0, kq);       // zeros for unused waves

    __syncthreads();                  // vmcnt(0) drain: init stores at LLC
    if (tid == 0) astore_u32(&done[w], 1u);

    // ==== main loop: superstep s computes layer0@s and layer1@s-1 ====
    for (int s = 0; s <= T_; ++s) {
        unsigned* h1p = h1r[(s + 1) & 1];
        unsigned* h1c = h1r[s & 1];
        unsigned* h2p = h2r[s & 1];
        unsigned* h2c = h2r[(s + 1) & 1];
        const bool do0 = (s < T_), do1 = (s > 0);

        f32x4 acc0[4], acc1[4];
        #pragma unroll
        for (int bt = 0; bt < 4; ++bt) { acc0[bt] = {0,0,0,0}; acc1[bt] = {0,0,0,0}; }

        // ---- x contribution (cached loads, overlaps nothing to wait for) ----
        if (v < 2 && do0) {
            #pragma unroll
            for (int bt = 0; bt < 4; ++bt) {
                const float* xrow = x + ((size_t)(bt * 16 + bl) * T_ + s) * F_;
                float xv[8];
                #pragma unroll
                for (int e = 0; e < 8; ++e) {
                    int col = v * 32 + kq * 8 + e;
                    xv[e] = (col < F_) ? xrow[col] : 0.0f;
                }
                Frag2 xb = split8(xv);
                acc0[bt] = mfma3(Ax, xb, acc0[bt]);
            }
        }

        // ---- all-wave epoch poll (RMW-free monotone flags) ----
        {
            const unsigned tgt = (unsigned)(s + 1);
            const unsigned* p = done + lane * 2;
            for (;;) {
                uint2 d = llc_load2(p);
                vm_wait0();
                if (__all((int)(min(d.x, d.y) >= tgt))) break;
                __builtin_amdgcn_s_sleep(1);
            }
        }

        // ---- 2-deep pipelined LLC loads + MFMA (wave v: k-tiles 2v,2v+1) ----
        const int kt0 = (2 * v) * 32, kt1 = (2 * v + 1) * 32;
        uint4 r1a[4][2], r1b[4][2], r2a[4][2], r2b[4][2];
        #pragma unroll
        for (int bt = 0; bt < 4; ++bt) {
            const unsigned* p = h1p + (bt * 16 + bl) * H_ + kt0 + kq * 8;
            r1a[bt][0] = llc_load4(p); r1a[bt][1] = llc_load4(p + 4);
        }
        #pragma unroll
        for (int bt = 0; bt < 4; ++bt) {
            const unsigned* p = h1p + (bt * 16 + bl) * H_ + kt1 + kq * 8;
            r1b[bt][0] = llc_load4(p); r1b[bt][1] = llc_load4(p + 4);
        }
        vm_wait8();                                  // r1a complete
        #pragma unroll
        for (int bt = 0; bt < 4; ++bt) {
            Frag2 hb = fromPacked(r1a[bt][0], r1a[bt][1]);
            if (do0) acc0[bt] = mfma3(A10[0], hb, acc0[bt]);
            if (do1) acc1[bt] = mfma3(A11[0], hb, acc1[bt]);
        }
        #pragma unroll
        for (int bt = 0; bt < 4; ++bt) {
            const unsigned* p = h2p + (bt * 16 + bl) * H_ + kt0 + kq * 8;
            r2a[bt][0] = llc_load4(p); r2a[bt][1] = llc_load4(p + 4);
        }
        vm_wait8();                                  // r1b complete
        #pragma unroll
        for (int bt = 0; bt < 4; ++bt) {
            Frag2 hb = fromPacked(r1b[bt][0], r1b[bt][1]);
            if (do0) acc0[bt] = mfma3(A10[1], hb, acc0[bt]);
            if (do1) acc1[bt] = mfma3(A11[1], hb, acc1[bt]);
        }
        #pragma unroll
        for (int bt = 0; bt < 4; ++bt) {
            const unsigned* p = h2p + (bt * 16 + bl) * H_ + kt1 + kq * 8;
            r2b[bt][0] = llc_load4(p); r2b[bt][1] = llc_load4(p + 4);
        }
        vm_wait8();                                  // r2a complete
        if (do1) {
            #pragma unroll
            for (int bt = 0; bt < 4; ++bt)
                acc1[bt] = mfma3(A21[0], fromPacked(r2a[bt][0], r2a[bt][1]), acc1[bt]);
        }
        vm_wait0();                                  // r2b complete
        if (do1) {
            #pragma unroll
            for (int bt = 0; bt < 4; ++bt)
                acc1[bt] = mfma3(A21[1], fromPacked(r2b[bt][0], r2b[bt][1]), acc1[bt]);
        }

        // ---- cross-wave reduction staging ----
        #pragma unroll
        for (int bt = 0; bt < 4; ++bt)
            #pragma unroll
            for (int reg = 0; reg < 4; ++reg) {
                parts[v][0][bt][reg][lane] = acc0[bt][reg];
                parts[v][1][bt][reg][lane] = acc1[bt][reg];
            }
        __syncthreads();

        // ---- B: gates + cell + h writeback. thread = (layer, unit, batch) ----
        {
            int layer = tid >> 8, uu = (tid >> 6) & 3, b = tid & 63;
            bool act = layer == 0 ? do0 : do1;
            if (act) {
                float pre[4];
                #pragma unroll
                for (int gg = 0; gg < 4; ++gg) {     // D row r=4g+u -> lane g*16+(b&15), reg u
                    float sum = bias[layer][gg][uu];
                    #pragma unroll
                    for (int wv = 0; wv < NW; ++wv)
                        sum += parts[wv][layer][b >> 4][uu][gg * 16 + (b & 15)];
                    pre[gg] = sum;
                }
                float ig = sigm(pre[0]), ff = sigm(pre[1]);
                float gv = tanhf_(pre[2]), og = sigm(pre[3]);
                float cc = fmaf(ff, cs[layer][uu][b], ig * gv);
                cs[layer][uu][b] = cc;
                unsigned hp = packhl(og * tanhf_(cc));
                unsigned* dst = (layer == 0 ? h1c : h2c) + b * H_ + (w * 4 + uu);
                astore_u32(dst, hp);
            }
        }
        __syncthreads();                             // vmcnt(0) drain: h stores at LLC
        if (tid == 0) astore_u32(&done[w], (unsigned)(s + 2));
    }

    // ---- final projection: out[b][c] = sum_k h2[b][k] Wout[c][k] + bout[c] ----
    if (w < C_) {
        {
            const unsigned tgt = (unsigned)(T_ + 2);
            const unsigned* p = done + lane * 2;
            for (;;) {
                uint2 d = llc_load2(p);
                vm_wait0();
                if (__all((int)(min(d.x, d.y) >= tgt))) break;
                __builtin_amdgcn_s_sleep(1);
            }
        }
        const unsigned* h2l = h2r[(T_ - 1) & 1];
        const float* wrow = Wout + (size_t)w * H_;
        uint4 q[16];
        #pragma unroll
        for (int i = 0; i < 16; ++i)
            q[i] = llc_load4(h2l + lane * H_ + v * 64 + i * 4);
        vm_wait0();
        float a = 0.0f;
        #pragma unroll
        for (int i = 0; i < 16; ++i) {
            unsigned pv[4] = { q[i].x, q[i].y, q[i].z, q[i].w };
            #pragma unroll
            for (int e = 0; e < 4; ++e) {
                int k = v * 64 + i * 4 + e;
                float hval = __uint_as_float(pv[e] << 16) + __uint_as_float(pv[e] & 0xFFFF0000u);
                a = fmaf(hval, wrow[k], a);
            }
        }
        parts[v][0][0][0][lane] = a;
        __syncthreads();
        if (v == 0) {
            float sum = bout[w];
            #pragma unroll
            for (int wv = 0; wv < NW; ++wv) sum += parts[wv][0][0][0][lane];
            out[lane * C_ + w] = sum;
        }
    }
}

extern "C" void kernel_launch(void* const* d_in, const int* in_sizes, int n_in,
                              void* d_out, int out_size, void* d_ws, size_t ws_size,
                              hipStream_t stream)
{
    const float* x    = (const float*)d_in[0];
    const float* Wih0 = (const float*)d_in[1];
    const float* Whh0 = (const float*)d_in[2];
    const float* bih0 = (const float*)d_in[3];
    const float* bhh0 = (const float*)d_in[4];
    const float* Wih1 = (const float*)d_in[5];
    const float* Whh1 = (const float*)d_in[6];
    const float* bih1 = (const float*)d_in[7];
    const float* bhh1 = (const float*)d_in[8];
    const float* Wout = (const float*)d_in[9];
    const float* bout = (const float*)d_in[10];
    float* out = (float*)d_out;
    unsigned* wsu = (unsigned*)d_ws;

    // reset epoch flags (in-graph, deterministic across replays)
    hipMemsetAsync(d_ws, 0, BAR_U32 * sizeof(unsigned), stream);

    void* args[] = { (void*)&x, (void*)&Wih0, (void*)&Whh0, (void*)&bih0, (void*)&bhh0,
                     (void*)&Wih1, (void*)&Whh1, (void*)&bih1, (void*)&bhh1,
                     (void*)&Wout, (void*)&bout, (void*)&out, (void*)&wsu };
    hipLaunchCooperativeKernel((void*)lstm_all, dim3(NWG), dim3(BLK), args, 0, stream);
}

// Round 11
// 20023.199 us; speedup vs baseline: 1.0994x; 1.0994x over previous
//
#include <hip/hip_runtime.h>

constexpr int F_ = 36;
constexpr int H_ = 512;
constexpr int B_ = 64;
constexpr int T_ = 1500;
constexpr int C_ = 64;
constexpr int NWG = 128;          // 4 hidden units per layer per WG (R6 green chassis)
constexpr int BLK = 512;
constexpr int NW = 8;

constexpr int RING = B_ * H_;              // 32768 u32 per ring
constexpr int FLGSTRIDE = 32;              // one flag per 128B line
constexpr unsigned FLGN_U32 = NWG * FLGSTRIDE;   // 4096 u32 = 16KB

#define SCOPE_AGENT __HIP_MEMORY_SCOPE_AGENT

typedef __attribute__((ext_vector_type(8))) short bf16x8;
typedef __attribute__((ext_vector_type(4))) float f32x4;
typedef __attribute__((ext_vector_type(4))) unsigned u32x4;

// ---- cross-XCD primitives (R5/R6-proven): sc0sc1 write-through + LLC loads ----
__device__ __forceinline__ void astore_u32(unsigned* p, unsigned v) {
    __hip_atomic_store(p, v, __ATOMIC_RELAXED, SCOPE_AGENT);
}
__device__ __forceinline__ uint4 llc_load4(const unsigned* p) {
    uint4 r;
    asm volatile("global_load_dwordx4 %0, %1, off sc0 sc1" : "=v"(r) : "v"(p));
    return r;
}
__device__ __forceinline__ unsigned llc_load1(const unsigned* p) {
    unsigned r;
    asm volatile("global_load_dword %0, %1, off sc0 sc1" : "=v"(r) : "v"(p));
    return r;
}
// store value must be a native ext_vector (struct inputs unsupported for "v")
__device__ __forceinline__ void gstore4(unsigned* p, u32x4 v) {
    asm volatile("global_store_dwordx4 %0, %1, off sc0 sc1" :: "v"(p), "v"(v) : "memory");
}
// rule #18: sched_barrier(0) after inline-asm waitcnt
__device__ __forceinline__ void vm_wait0()  { asm volatile("s_waitcnt vmcnt(0)"  ::: "memory"); __builtin_amdgcn_sched_barrier(0); }
__device__ __forceinline__ void vm_wait8()  { asm volatile("s_waitcnt vmcnt(8)"  ::: "memory"); __builtin_amdgcn_sched_barrier(0); }
__device__ __forceinline__ void vm_wait16() { asm volatile("s_waitcnt vmcnt(16)" ::: "memory"); __builtin_amdgcn_sched_barrier(0); }
__device__ __forceinline__ void vm_wait24() { asm volatile("s_waitcnt vmcnt(24)" ::: "memory"); __builtin_amdgcn_sched_barrier(0); }

__device__ __forceinline__ float sigm(float x) { return 1.0f / (1.0f + __expf(-x)); }
__device__ __forceinline__ float tanhf_(float x) { return 1.0f - 2.0f / (__expf(2.0f * x) + 1.0f); }

// ---- bf16 hi/lo split machinery (R6-proven) ----
__device__ __forceinline__ unsigned bf16rne(float f) {
    unsigned u = __float_as_uint(f);
    return (u + 0x7FFFu + ((u >> 16) & 1u)) >> 16;
}
__device__ __forceinline__ unsigned packhl(float h) {
    unsigned hi = bf16rne(h);
    float lo = h - __uint_as_float(hi << 16);
    return hi | (bf16rne(lo) << 16);
}

struct Frag2 { bf16x8 hi, lo; };

__device__ __forceinline__ Frag2 split8(const float v[8]) {
    union { unsigned u[4]; bf16x8 x; } hi, lo;
    #pragma unroll
    for (int j = 0; j < 4; ++j) {
        unsigned a = bf16rne(v[2*j]), b = bf16rne(v[2*j+1]);
        float ra = v[2*j]   - __uint_as_float(a << 16);
        float rb = v[2*j+1] - __uint_as_float(b << 16);
        hi.u[j] = a | (b << 16);
        lo.u[j] = bf16rne(ra) | (bf16rne(rb) << 16);
    }
    return { hi.x, lo.x };
}
__device__ __forceinline__ Frag2 fromPacked(const uint4& q0, const uint4& q1) {
    unsigned p[8] = { q0.x, q0.y, q0.z, q0.w, q1.x, q1.y, q1.z, q1.w };
    union { unsigned u[4]; bf16x8 x; } hi, lo;
    #pragma unroll
    for (int j = 0; j < 4; ++j) {
        hi.u[j] = (p[2*j] & 0xFFFFu) | (p[2*j+1] << 16);
        lo.u[j] = (p[2*j] >> 16) | (p[2*j+1] & 0xFFFF0000u);
    }
    return { hi.x, lo.x };
}
__device__ __forceinline__ f32x4 mfma3(const Frag2& a, const Frag2& b, f32x4 c) {
    c = __builtin_amdgcn_mfma_f32_16x16x32_bf16(a.hi, b.hi, c, 0, 0, 0);
    c = __builtin_amdgcn_mfma_f32_16x16x32_bf16(a.hi, b.lo, c, 0, 0, 0);
    c = __builtin_amdgcn_mfma_f32_16x16x32_bf16(a.lo, b.hi, c, 0, 0, 0);
    return c;
}
__device__ Frag2 gatherA(const float* W, int rstride, int grow, int colbase, int ncols, int kq) {
    float v[8];
    #pragma unroll
    for (int e = 0; e < 8; ++e) {
        int col = colbase + kq * 8 + e;
        v[e] = (col < ncols) ? W[(size_t)grow * rstride + col] : 0.0f;
    }
    return split8(v);
}

// all-wave poll of 128 line-padded monotone epoch flags (2 dword loads/lane)
__device__ __forceinline__ void pollPad(const unsigned* flags, unsigned tgt, int lane) {
    const unsigned* p0 = flags + lane * FLGSTRIDE;
    const unsigned* p1 = flags + (64 + lane) * FLGSTRIDE;
    for (;;) {
        unsigned a = llc_load1(p0);
        unsigned b = llc_load1(p1);
        vm_wait0();
        if (__all((int)(min(a, b) >= tgt))) break;
    }
}

__global__ void __launch_bounds__(BLK, 1) lstm_all(
    const float* __restrict__ x,
    const float* __restrict__ Wih0, const float* __restrict__ Whh0,
    const float* __restrict__ bih0, const float* __restrict__ bhh0,
    const float* __restrict__ Wih1, const float* __restrict__ Whh1,
    const float* __restrict__ bih1, const float* __restrict__ bhh1,
    const float* __restrict__ Wout, const float* __restrict__ bout,
    float* __restrict__ out, unsigned* __restrict__ wsu)
{
    const int w = blockIdx.x;
    const int tid = threadIdx.x;
    const int v = tid >> 6;          // wave 0..7
    const int lane = tid & 63;
    const int bl = lane & 15;        // A-row / batch-local index
    const int kq = lane >> 4;        // k-quarter within frag

    __shared__ float parts[NW][2][4][4][65];   // [wave][layer][bt][reg][lane(+pad)]
    __shared__ float cs[2][4][64];             // cell state [layer][unit][b]
    __shared__ float bias[2][4][4];            // [layer][gate][unit]
    __shared__ unsigned hstage[2][4][64];      // packed h staging [layer][unit][b]

    unsigned* flags = wsu;                     // line-padded: flag[w] at w*FLGSTRIDE
    unsigned* ringb = wsu + FLGN_U32;
    unsigned* h1r[2] = { ringb, ringb + RING };
    unsigned* h2r[2] = { ringb + 2 * RING, ringb + 3 * RING };

    // ---- init: zero rings, cs, bias ----
    {
        const int gstride = NWG * BLK;
        for (int i = w * BLK + tid; i < 4 * RING; i += gstride)
            astore_u32(ringb + i, 0u);
    }
    ((float*)cs)[tid] = 0.0f;                  // 2*4*64 == 512 == BLK
    if (tid < 32) {
        int layer = tid >> 4, g = (tid >> 2) & 3, u = tid & 3;
        int grow = g * H_ + w * 4 + u;
        bias[layer][g][u] = layer ? (bih1[grow] + bhh1[grow]) : (bih0[grow] + bhh0[grow]);
    }

    // ---- one-time A-fragments (weights stay in VGPRs; R6-proven mapping) ----
    const int grow = (bl >> 2) * H_ + w * 4 + (bl & 3);
    Frag2 A10[2], A11[2], A21[2], Ax{};
    #pragma unroll
    for (int i = 0; i < 2; ++i) {
        int cb = (2 * v + i) * 32;
        A10[i] = gatherA(Whh0, H_, grow, cb, H_, kq);
        A11[i] = gatherA(Wih1, H_, grow, cb, H_, kq);
        A21[i] = gatherA(Whh1, H_, grow, cb, H_, kq);
    }
    if (v < 2) Ax = gatherA(Wih0, F_, grow, v * 32, F_, kq);

    __syncthreads();                  // init stores drained before flag
    if (tid == 0) astore_u32(&flags[w * FLGSTRIDE], 1u);

    uint4 r1a[8], r1b[8], r2a[8], r2b[8];

    for (int s = 0; s <= T_; ++s) {
        const bool do0 = (s < T_), do1 = (s > 0);
        unsigned* h1p = h1r[(s + 1) & 1];
        unsigned* h1c = h1r[s & 1];
        unsigned* h2p = h2r[s & 1];
        unsigned* h2c = h2r[(s + 1) & 1];

        f32x4 acc0[4] = {{0,0,0,0},{0,0,0,0},{0,0,0,0},{0,0,0,0}};
        f32x4 acc1[4] = {{0,0,0,0},{0,0,0,0},{0,0,0,0},{0,0,0,0}};

        // ---- x contribution (pre-poll; plain vectorized loads, R6 position) ----
        if (do0 && v < 2) {
            #pragma unroll
            for (int bt = 0; bt < 4; ++bt) {
                const float4* xr = reinterpret_cast<const float4*>(
                    x + ((size_t)(bt * 16 + bl) * T_ + s) * F_);
                float xv[8] = {0,0,0,0,0,0,0,0};
                if (v == 0) {
                    float4 a = xr[kq * 2], b4 = xr[kq * 2 + 1];
                    xv[0]=a.x; xv[1]=a.y; xv[2]=a.z; xv[3]=a.w;
                    xv[4]=b4.x; xv[5]=b4.y; xv[6]=b4.z; xv[7]=b4.w;
                } else if (kq == 0) {
                    float4 a = xr[8];                    // cols 32..35
                    xv[0]=a.x; xv[1]=a.y; xv[2]=a.z; xv[3]=a.w;
                }
                acc0[bt] = mfma3(Ax, split8(xv), acc0[bt]);
            }
        }

        // ---- wait for step s-1 everywhere (tight, line-padded poll) ----
        pollPad(flags, (unsigned)(s + 1), lane);

        // ---- issue ALL 32 LLC loads upfront; counted waits 24/16/8/0 ----
        #pragma unroll
        for (int bt = 0; bt < 4; ++bt) {
            const unsigned* p = h1p + (bt*16 + bl) * H_ + (2*v)*32 + kq*8;
            r1a[bt*2] = llc_load4(p); r1a[bt*2+1] = llc_load4(p + 4);
        }
        #pragma unroll
        for (int bt = 0; bt < 4; ++bt) {
            const unsigned* p = h1p + (bt*16 + bl) * H_ + (2*v+1)*32 + kq*8;
            r1b[bt*2] = llc_load4(p); r1b[bt*2+1] = llc_load4(p + 4);
        }
        #pragma unroll
        for (int bt = 0; bt < 4; ++bt) {
            const unsigned* p = h2p + (bt*16 + bl) * H_ + (2*v)*32 + kq*8;
            r2a[bt*2] = llc_load4(p); r2a[bt*2+1] = llc_load4(p + 4);
        }
        #pragma unroll
        for (int bt = 0; bt < 4; ++bt) {
            const unsigned* p = h2p + (bt*16 + bl) * H_ + (2*v+1)*32 + kq*8;
            r2b[bt*2] = llc_load4(p); r2b[bt*2+1] = llc_load4(p + 4);
        }

        vm_wait24();                               // r1a ready
        #pragma unroll
        for (int bt = 0; bt < 4; ++bt) {
            Frag2 hb = fromPacked(r1a[bt*2], r1a[bt*2+1]);
            if (do0) acc0[bt] = mfma3(A10[0], hb, acc0[bt]);
            if (do1) acc1[bt] = mfma3(A11[0], hb, acc1[bt]);
        }
        vm_wait16();                               // r1b ready
        #pragma unroll
        for (int bt = 0; bt < 4; ++bt) {
            Frag2 hb = fromPacked(r1b[bt*2], r1b[bt*2+1]);
            if (do0) acc0[bt] = mfma3(A10[1], hb, acc0[bt]);
            if (do1) acc1[bt] = mfma3(A11[1], hb, acc1[bt]);
        }
        vm_wait8();                                // r2a ready
        if (do1) {
            #pragma unroll
            for (int bt = 0; bt < 4; ++bt)
                acc1[bt] = mfma3(A21[0], fromPacked(r2a[bt*2], r2a[bt*2+1]), acc1[bt]);
        }
        vm_wait0();                                // r2b ready
        if (do1) {
            #pragma unroll
            for (int bt = 0; bt < 4; ++bt)
                acc1[bt] = mfma3(A21[1], fromPacked(r2b[bt*2], r2b[bt*2+1]), acc1[bt]);
        }

        // ---- cross-wave reduction staging ----
        #pragma unroll
        for (int bt = 0; bt < 4; ++bt)
            #pragma unroll
            for (int rg = 0; rg < 4; ++rg) {
                parts[v][0][bt][rg][lane] = acc0[bt][rg];
                parts[v][1][bt][rg][lane] = acc1[bt][rg];
            }
        __syncthreads();

        // ---- B: gates + cell; h into LDS staging (no scattered global stores) ----
        {
            int layer = tid >> 8, uu = (tid >> 6) & 3, b = tid & 63;
            bool actL = (layer == 0) ? do0 : do1;
            if (actL) {
                float pre[4];
                #pragma unroll
                for (int gg = 0; gg < 4; ++gg) {
                    float sum = bias[layer][gg][uu];
                    #pragma unroll
                    for (int wv = 0; wv < NW; ++wv)
                        sum += parts[wv][layer][b >> 4][uu][gg * 16 + (b & 15)];
                    pre[gg] = sum;
                }
                float ig = sigm(pre[0]), ff = sigm(pre[1]);
                float gv = tanhf_(pre[2]), og = sigm(pre[3]);
                float cc = fmaf(ff, cs[layer][uu][b], ig * gv);
                cs[layer][uu][b] = cc;
                hstage[layer][uu][b] = packhl(og * tanhf_(cc));
            }
        }
        __syncthreads();

        // ---- coalesced h writeback: one 16B sc0sc1 store per (layer, b) ----
        if (tid < 128) {
            int layer = tid >> 6, b = tid & 63;
            bool actL = (layer == 0) ? do0 : do1;
            if (actL) {
                u32x4 q = { hstage[layer][0][b], hstage[layer][1][b],
                            hstage[layer][2][b], hstage[layer][3][b] };
                gstore4((layer == 0 ? h1c : h2c) + b * H_ + w * 4, q);
            }
            vm_wait0();                            // asm stores drained at LLC
        }
        __syncthreads();
        if (tid == 0) astore_u32(&flags[w * FLGSTRIDE], (unsigned)(s + 2));
    }

    // ---- final projection: out[b][c] = h2[T-1][b] . Wout[c] + bout[c] ----
    if (w < C_) {
        pollPad(flags, (unsigned)(T_ + 2), lane);
        const unsigned* h2l = h2r[(T_ + 1) & 1];   // h2[T-1]
        const float* wrow = Wout + (size_t)w * H_;
        uint4 q[16];
        #pragma unroll
        for (int i = 0; i < 16; ++i)
            q[i] = llc_load4(h2l + lane * H_ + v * 64 + i * 4);
        vm_wait0();
        float a = 0.0f;
        #pragma unroll
        for (int i = 0; i < 16; ++i) {
            unsigned pv[4] = { q[i].x, q[i].y, q[i].z, q[i].w };
            #pragma unroll
            for (int e = 0; e < 4; ++e) {
                float hv = __uint_as_float(pv[e] << 16) + __uint_as_float(pv[e] & 0xFFFF0000u);
                a = fmaf(hv, wrow[v * 64 + i * 4 + e], a);
            }
        }
        parts[v][0][0][0][lane] = a;
        __syncthreads();
        if (v == 0) {
            float sum = bout[w];
            #pragma unroll
            for (int wv = 0; wv < NW; ++wv) sum += parts[wv][0][0][0][lane];
            out[lane * C_ + w] = sum;
        }
    }
}

extern "C" void kernel_launch(void* const* d_in, const int* in_sizes, int n_in,
                              void* d_out, int out_size, void* d_ws, size_t ws_size,
                              hipStream_t stream)
{
    const float* x    = (const float*)d_in[0];
    const float* Wih0 = (const float*)d_in[1];
    const float* Whh0 = (const float*)d_in[2];
    const float* bih0 = (const float*)d_in[3];
    const float* bhh0 = (const float*)d_in[4];
    const float* Wih1 = (const float*)d_in[5];
    const float* Whh1 = (const float*)d_in[6];
    const float* bih1 = (const float*)d_in[7];
    const float* bhh1 = (const float*)d_in[8];
    const float* Wout = (const float*)d_in[9];
    const float* bout = (const float*)d_in[10];
    float* out = (float*)d_out;
    unsigned* wsu = (unsigned*)d_ws;

    // reset padded epoch flags (in-graph, deterministic across replays)
    (void)hipMemsetAsync(d_ws, 0, FLGN_U32 * sizeof(unsigned), stream);

    void* args[] = { (void*)&x, (void*)&Wih0, (void*)&Whh0, (void*)&bih0, (void*)&bhh0,
                     (void*)&Wih1, (void*)&Whh1, (void*)&bih1, (void*)&bhh1,
                     (void*)&Wout, (void*)&bout, (void*)&out, (void*)&wsu };
    (void)hipLaunchCooperativeKernel((void*)lstm_all, dim3(NWG), dim3(BLK), args, 0, stream);
}